// Round 1
// baseline (956.272 us; speedup 1.0000x reference)
//
#include <hip/hip_runtime.h>
#include <hip/hip_bf16.h>

#define NN 20000
#define EE 160000
#define ETOT 180000   // edges + self loops
#define HH 8
#define DD 512
#define CC 64
#define GG 128
#define OUTD 128

// ---------------- CSR build ----------------

__global__ void k_degree(const int* __restrict__ ei, int* __restrict__ deg) {
    int e = blockIdx.x * blockDim.x + threadIdx.x;
    if (e >= ETOT) return;
    int dst = (e < EE) ? ei[EE + e] : (e - EE);
    atomicAdd(&deg[dst], 1);
}

__global__ __launch_bounds__(1024) void k_scan(const int* __restrict__ deg,
                                               int* __restrict__ rowptr) {
    __shared__ int part[1024];
    const int n = NN;
    const int per = (n + 1023) / 1024;
    int base = threadIdx.x * per;
    int s = 0;
    for (int i = 0; i < per; i++) {
        int idx = base + i;
        if (idx < n) s += deg[idx];
    }
    part[threadIdx.x] = s;
    __syncthreads();
    for (int off = 1; off < 1024; off <<= 1) {
        int v = 0;
        if ((int)threadIdx.x >= off) v = part[threadIdx.x - off];
        __syncthreads();
        part[threadIdx.x] += v;
        __syncthreads();
    }
    int run = (threadIdx.x == 0) ? 0 : part[threadIdx.x - 1];
    for (int i = 0; i < per; i++) {
        int idx = base + i;
        if (idx < n) { rowptr[idx] = run; run += deg[idx]; }
    }
    if (threadIdx.x == 1023) rowptr[n] = part[1023];
}

__global__ void k_scatter(const int* __restrict__ ei, int* __restrict__ wp,
                          int* __restrict__ csr) {
    int e = blockIdx.x * blockDim.x + threadIdx.x;
    if (e >= ETOT) return;
    int src, dst;
    if (e < EE) { src = ei[e]; dst = ei[EE + e]; }
    else        { src = e - EE; dst = e - EE; }
    int pos = atomicAdd(&wp[dst], 1);
    csr[pos] = src;
}

// ---------------- GEMM: C(MxK) = A(MxK=512) * B(512x512) ----------------

__global__ __launch_bounds__(256) void k_gemm(const float* __restrict__ A,
                                              const float* __restrict__ B,
                                              float* __restrict__ Cout, int M) {
    __shared__ float As[16][68];
    __shared__ float Bs[16][68];
    int tid = threadIdx.x;
    int row0 = blockIdx.x * 64, col0 = blockIdx.y * 64;
    int tx = tid & 15, ty = tid >> 4;
    int lm = tid >> 2, lk = (tid & 3) * 4;   // A-tile load: row lm, 4 k's
    int bk = tid >> 4, bc = (tid & 15) * 4;  // B-tile load: row bk, 4 cols
    float acc[4][4] = {};
    for (int k0 = 0; k0 < 512; k0 += 16) {
        float4 av = make_float4(0.f, 0.f, 0.f, 0.f);
        int ar = row0 + lm;
        if (ar < M) av = *reinterpret_cast<const float4*>(&A[ar * 512 + k0 + lk]);
        float4 bv = *reinterpret_cast<const float4*>(&B[(k0 + bk) * 512 + col0 + bc]);
        As[lk + 0][lm] = av.x; As[lk + 1][lm] = av.y;
        As[lk + 2][lm] = av.z; As[lk + 3][lm] = av.w;
        *reinterpret_cast<float4*>(&Bs[bk][bc]) = bv;
        __syncthreads();
#pragma unroll
        for (int kk = 0; kk < 16; kk++) {
            float4 a = *reinterpret_cast<const float4*>(&As[kk][ty * 4]);
            float4 b = *reinterpret_cast<const float4*>(&Bs[kk][tx * 4]);
            float aa[4] = {a.x, a.y, a.z, a.w};
            float bb[4] = {b.x, b.y, b.z, b.w};
#pragma unroll
            for (int i = 0; i < 4; i++)
#pragma unroll
                for (int j = 0; j < 4; j++) acc[i][j] += aa[i] * bb[j];
        }
        __syncthreads();
    }
#pragma unroll
    for (int i = 0; i < 4; i++) {
        int r = row0 + ty * 4 + i;
        if (r < M) {
#pragma unroll
            for (int j = 0; j < 4; j++)
                Cout[r * 512 + col0 + tx * 4 + j] = acc[i][j];
        }
    }
}

// ---------------- attention scores: es/ed[n][h] = dot(h[n,h,:], a) ----------------

__global__ __launch_bounds__(256) void k_scores(const float* __restrict__ h,
                                                const float* __restrict__ a_s,
                                                const float* __restrict__ a_d,
                                                float* __restrict__ es,
                                                float* __restrict__ ed) {
    int wid = (blockIdx.x * 256 + threadIdx.x) >> 6;
    int lane = threadIdx.x & 63;
    if (wid >= NN * HH) return;
    int n = wid >> 3, hh = wid & 7;
    float v = h[n * DD + hh * CC + lane];
    float ps = v * a_s[hh * CC + lane];
    float pd = v * a_d[hh * CC + lane];
#pragma unroll
    for (int off = 32; off > 0; off >>= 1) {
        ps += __shfl_down(ps, off);
        pd += __shfl_down(pd, off);
    }
    if (lane == 0) { es[wid] = ps; ed[wid] = pd; }
}

// ---------------- GAT aggregation + bias + LayerNorm + ReLU (per dst node) ----------------

__global__ __launch_bounds__(256) void k_gat_agg(const float* __restrict__ h,
                                                 const float* __restrict__ es,
                                                 const float* __restrict__ ed,
                                                 const int* __restrict__ rowptr,
                                                 const int* __restrict__ csr,
                                                 const float* __restrict__ bias,
                                                 const float* __restrict__ gamma,
                                                 const float* __restrict__ beta,
                                                 float* __restrict__ xout) {
    int n = blockIdx.x;
    int tid = threadIdx.x;
    int r0 = rowptr[n], r1 = rowptr[n + 1];
    int deg = r1 - r0;

    __shared__ float s_edn[8];
    __shared__ int s_src[64];
    __shared__ float s_p[64][8];
    __shared__ float s_m[8], s_sum[8], s_scale[8];
    __shared__ float red[256];

    if (tid < 8) { s_edn[tid] = ed[n * 8 + tid]; s_m[tid] = -1e30f; s_sum[tid] = 0.f; }
    float acc0 = 0.f, acc1 = 0.f;
    int head0 = tid >> 6;
    int head1 = (tid + 256) >> 6;
    __syncthreads();

    for (int cb = 0; cb < deg; cb += 64) {
        int cnt = min(64, deg - cb);
        if (tid < cnt) s_src[tid] = csr[r0 + cb + tid];
        __syncthreads();
        for (int idx = tid; idx < cnt * 8; idx += 256) {
            int j = idx >> 3, hh2 = idx & 7;
            float e = es[s_src[j] * 8 + hh2] + s_edn[hh2];
            e = (e >= 0.f) ? e : 0.2f * e;
            s_p[j][hh2] = e;
        }
        __syncthreads();
        if (tid < 8) {
            int hh2 = tid;
            float cm = -1e30f;
            for (int j = 0; j < cnt; j++) cm = fmaxf(cm, s_p[j][hh2]);
            float m_old = s_m[hh2];
            float m_new = fmaxf(m_old, cm);
            float scale = __expf(m_old - m_new);
            float csum = 0.f;
            for (int j = 0; j < cnt; j++) {
                float p = __expf(s_p[j][hh2] - m_new);
                s_p[j][hh2] = p;
                csum += p;
            }
            s_sum[hh2] = s_sum[hh2] * scale + csum;
            s_m[hh2] = m_new;
            s_scale[hh2] = scale;
        }
        __syncthreads();
        acc0 *= s_scale[head0];
        acc1 *= s_scale[head1];
        for (int j = 0; j < cnt; j++) {
            int s = s_src[j];
            acc0 += s_p[j][head0] * h[s * DD + tid];
            acc1 += s_p[j][head1] * h[s * DD + tid + 256];
        }
        __syncthreads();
    }

    float o0 = acc0 / (s_sum[head0] + 1e-16f) + bias[tid];
    float o1 = acc1 / (s_sum[head1] + 1e-16f) + bias[tid + 256];

    // LayerNorm over 512 dims
    red[tid] = o0 + o1;
    __syncthreads();
    for (int off = 128; off > 0; off >>= 1) {
        if (tid < off) red[tid] += red[tid + off];
        __syncthreads();
    }
    float mu = red[0] * (1.f / 512.f);
    __syncthreads();
    float d0 = o0 - mu, d1 = o1 - mu;
    red[tid] = d0 * d0 + d1 * d1;
    __syncthreads();
    for (int off = 128; off > 0; off >>= 1) {
        if (tid < off) red[tid] += red[tid + off];
        __syncthreads();
    }
    float var = red[0] * (1.f / 512.f);
    float rs = rsqrtf(var + 1e-5f);
    float y0 = d0 * rs * gamma[tid] + beta[tid];
    float y1 = d1 * rs * gamma[tid + 256] + beta[tid + 256];
    xout[n * DD + tid] = fmaxf(y0, 0.f);
    xout[n * DD + tid + 256] = fmaxf(y1, 0.f);
}

// ---------------- pooling + FC ----------------

__global__ void k_gbounds(const int* __restrict__ batch, int* __restrict__ gstart) {
    int g = blockIdx.x * blockDim.x + threadIdx.x;
    if (g > GG) return;
    int lo = 0, hi = NN;
    while (lo < hi) {
        int mid = (lo + hi) >> 1;
        if (batch[mid] < g) lo = mid + 1; else hi = mid;
    }
    gstart[g] = lo;
}

__global__ __launch_bounds__(256) void k_pool(const float* __restrict__ x,
                                              const int* __restrict__ gstart,
                                              float* __restrict__ pooled) {
    int g = blockIdx.x, tid = threadIdx.x;
    int s = gstart[g], e = gstart[g + 1];
    float a0 = 0.f, a1 = 0.f;
    for (int n = s; n < e; n++) {
        a0 += x[n * DD + tid];
        a1 += x[n * DD + tid + 256];
    }
    float inv = 1.f / fmaxf((float)(e - s), 1.f);
    pooled[g * DD + tid] = a0 * inv;
    pooled[g * DD + tid + 256] = a1 * inv;
}

__global__ __launch_bounds__(128) void k_fc(const float* __restrict__ pooled,
                                            const float* __restrict__ Wf,
                                            const float* __restrict__ bf,
                                            float* __restrict__ out) {
    int g = blockIdx.x, o = threadIdx.x;
    __shared__ float row[DD];
    for (int i = o; i < DD; i += 128) row[i] = pooled[g * DD + i];
    __syncthreads();
    float acc = bf[o];
    for (int d = 0; d < DD; d++) acc += row[d] * Wf[d * OUTD + o];
    out[g * OUTD + o] = acc;
}

// ---------------- launch ----------------

extern "C" void kernel_launch(void* const* d_in, const int* in_sizes, int n_in,
                              void* d_out, int out_size, void* d_ws, size_t ws_size,
                              hipStream_t stream) {
    const float* x     = (const float*)d_in[0];
    const int*   ei    = (const int*)d_in[1];
    const int*   batch = (const int*)d_in[2];
    const float* W[3]  = {(const float*)d_in[3], (const float*)d_in[9],  (const float*)d_in[15]};
    const float* As[3] = {(const float*)d_in[4], (const float*)d_in[10], (const float*)d_in[16]};
    const float* Ad[3] = {(const float*)d_in[5], (const float*)d_in[11], (const float*)d_in[17]};
    const float* Bi[3] = {(const float*)d_in[6], (const float*)d_in[12], (const float*)d_in[18]};
    const float* Ga[3] = {(const float*)d_in[7], (const float*)d_in[13], (const float*)d_in[19]};
    const float* Be[3] = {(const float*)d_in[8], (const float*)d_in[14], (const float*)d_in[20]};
    const float* fcW = (const float*)d_in[21];
    const float* fcb = (const float*)d_in[22];
    float* out = (float*)d_out;

    // workspace carve (aligned to 256B)
    char* p = (char*)d_ws;
    auto carve = [&](size_t bytes) {
        char* r = p;
        p += (bytes + 255) & ~((size_t)255);
        return r;
    };
    float* bufA   = (float*)carve((size_t)NN * DD * 4);
    float* bufB   = (float*)carve((size_t)NN * DD * 4);
    float* es     = (float*)carve((size_t)NN * HH * 4);
    float* ed     = (float*)carve((size_t)NN * HH * 4);
    int*   deg    = (int*)carve((size_t)NN * 4);
    int*   rowptr = (int*)carve((size_t)(NN + 1) * 4);
    int*   wp     = (int*)carve((size_t)NN * 4);
    int*   csr    = (int*)carve((size_t)ETOT * 4);
    int*   gstart = (int*)carve((size_t)(GG + 1) * 4);
    float* pooled = (float*)carve((size_t)GG * DD * 4);

    // CSR build (per call; ws is re-poisoned each call)
    hipMemsetAsync(deg, 0, (size_t)NN * 4, stream);
    k_degree<<<(ETOT + 255) / 256, 256, 0, stream>>>(ei, deg);
    k_scan<<<1, 1024, 0, stream>>>(deg, rowptr);
    hipMemcpyAsync(wp, rowptr, (size_t)NN * 4, hipMemcpyDeviceToDevice, stream);
    k_scatter<<<(ETOT + 255) / 256, 256, 0, stream>>>(ei, wp, csr);
    k_gbounds<<<1, 256, 0, stream>>>(batch, gstart);

    const float* xin = x;
    for (int l = 0; l < 3; l++) {
        k_gemm<<<dim3((NN + 63) / 64, 8), 256, 0, stream>>>(xin, W[l], bufA, NN);
        k_scores<<<(NN * HH) / 4, 256, 0, stream>>>(bufA, As[l], Ad[l], es, ed);
        k_gat_agg<<<NN, 256, 0, stream>>>(bufA, es, ed, rowptr, csr,
                                          Bi[l], Ga[l], Be[l], bufB);
        xin = bufB;
    }

    k_pool<<<GG, 256, 0, stream>>>(bufB, gstart, pooled);
    k_fc<<<GG, 128, 0, stream>>>(pooled, fcW, fcb, out);
}

// Round 4
// 564.451 us; speedup vs baseline: 1.6942x; 1.6942x over previous
//
#include <hip/hip_runtime.h>
#include <hip/hip_bf16.h>

#define NN 20000
#define MPAD 20096          // 157 * 128
#define EE 160000
#define ETOT 180000         // edges + self loops
#define HH 8
#define DD 512
#define CC 64
#define GG 128
#define OUTD 128

typedef __bf16 bf16x8 __attribute__((ext_vector_type(8)));
typedef float f32x4 __attribute__((ext_vector_type(4)));

__device__ __forceinline__ float bf2f(unsigned short u) {
    unsigned int x = ((unsigned int)u) << 16;
    return __builtin_bit_cast(float, x);
}
__device__ __forceinline__ unsigned short f2bf(float f) {
    unsigned int x = __builtin_bit_cast(unsigned int, f);
    unsigned int r = (x + 0x7fff + ((x >> 16) & 1)) >> 16;
    return (unsigned short)r;
}

// ---------------- CSR build ----------------

__global__ void k_degree(const int* __restrict__ ei, int* __restrict__ deg) {
    int e = blockIdx.x * blockDim.x + threadIdx.x;
    if (e >= ETOT) return;
    int dst = (e < EE) ? ei[EE + e] : (e - EE);
    atomicAdd(&deg[dst], 1);
}

__global__ __launch_bounds__(1024) void k_scan(const int* __restrict__ deg,
                                               int* __restrict__ rowptr) {
    __shared__ int part[1024];
    const int n = NN;
    const int per = (n + 1023) / 1024;
    int base = threadIdx.x * per;
    int s = 0;
    for (int i = 0; i < per; i++) {
        int idx = base + i;
        if (idx < n) s += deg[idx];
    }
    part[threadIdx.x] = s;
    __syncthreads();
    for (int off = 1; off < 1024; off <<= 1) {
        int v = 0;
        if ((int)threadIdx.x >= off) v = part[threadIdx.x - off];
        __syncthreads();
        part[threadIdx.x] += v;
        __syncthreads();
    }
    int run = (threadIdx.x == 0) ? 0 : part[threadIdx.x - 1];
    for (int i = 0; i < per; i++) {
        int idx = base + i;
        if (idx < n) { rowptr[idx] = run; run += deg[idx]; }
    }
    if (threadIdx.x == 1023) rowptr[n] = part[1023];
}

__global__ void k_scatter(const int* __restrict__ ei, int* __restrict__ wp,
                          int* __restrict__ csr) {
    int e = blockIdx.x * blockDim.x + threadIdx.x;
    if (e >= ETOT) return;
    int src, dst;
    if (e < EE) { src = ei[e]; dst = ei[EE + e]; }
    else        { src = e - EE; dst = e - EE; }
    int pos = atomicAdd(&wp[dst], 1);
    csr[pos] = src;
}

// ---------------- f32 -> bf16 cast (with zero pad rows) ----------------

__global__ __launch_bounds__(256) void k_cast_x(const float* __restrict__ x,
                                                unsigned short* __restrict__ xb) {
    long long i = (long long)(blockIdx.x * 256 + threadIdx.x) * 4;
    if (i >= (long long)MPAD * DD) return;
    ushort4 o;
    if (i < (long long)NN * DD) {
        float4 v = *reinterpret_cast<const float4*>(&x[i]);
        o.x = f2bf(v.x); o.y = f2bf(v.y); o.z = f2bf(v.z); o.w = f2bf(v.w);
    } else {
        o = make_ushort4(0, 0, 0, 0);
    }
    *reinterpret_cast<ushort4*>(&xb[i]) = o;
}

// ---------------- W transpose + cast: Wt[n][k] = bf16(W[k][n]) ----------------

__global__ __launch_bounds__(256) void k_wt(const float* __restrict__ W,
                                            unsigned short* __restrict__ Wt) {
    __shared__ float t[32][33];
    int tx = threadIdx.x, ty = threadIdx.y;
    int bk = blockIdx.x * 32, bn = blockIdx.y * 32;
#pragma unroll
    for (int j = 0; j < 4; j++)
        t[ty + j * 8][tx] = W[(bk + ty + j * 8) * DD + bn + tx];
    __syncthreads();
#pragma unroll
    for (int j = 0; j < 4; j++)
        Wt[(bn + ty + j * 8) * DD + bk + tx] = f2bf(t[tx][ty + j * 8]);
}

// ---------------- bf16 MFMA GEMM: C[MPAD x 512] = A[MPAD x 512] * Bt^T ----------------
// m97 structure: 128x128 tile, BK=32, 4 waves (2x2), 16x16x32 MFMA, global_load_lds w16.

__global__ __launch_bounds__(256) void k_gemm(const unsigned short* __restrict__ A,
                                              const unsigned short* __restrict__ Bt,
                                              unsigned short* __restrict__ C) {
    __shared__ alignas(16) unsigned short As[128 * 32];
    __shared__ alignas(16) unsigned short Bs[128 * 32];
    int tid = threadIdx.x;
    int lane = tid & 63, wv = tid >> 6;
    int row0 = blockIdx.x * 128, col0 = blockIdx.y * 128;
    int wr = (wv >> 1) * 64, wc = (wv & 1) * 64;
    f32x4 acc[4][4] = {};
    int srow = lane >> 2;           // row within 16-row chunk
    int sel = (lane & 3) * 8;       // element offset (16B slot)

    for (int k0 = 0; k0 < DD; k0 += 32) {
#pragma unroll
        for (int i = 0; i < 2; i++) {
            int tr = wv * 32 + i * 16 + srow;
            __builtin_amdgcn_global_load_lds(
                (const __attribute__((address_space(1))) unsigned int*)&A[(size_t)(row0 + tr) * DD + k0 + sel],
                (__attribute__((address_space(3))) unsigned int*)&As[(wv * 32 + i * 16) * 32],
                16, 0, 0);
            __builtin_amdgcn_global_load_lds(
                (const __attribute__((address_space(1))) unsigned int*)&Bt[(size_t)(col0 + tr) * DD + k0 + sel],
                (__attribute__((address_space(3))) unsigned int*)&Bs[(wv * 32 + i * 16) * 32],
                16, 0, 0);
        }
        __syncthreads();
        bf16x8 af[4], bfv[4];
        int rsel = lane & 15, g = (lane >> 4) * 8;
#pragma unroll
        for (int m = 0; m < 4; m++)
            af[m] = *reinterpret_cast<const bf16x8*>(&As[(wr + m * 16 + rsel) * 32 + g]);
#pragma unroll
        for (int n2 = 0; n2 < 4; n2++)
            bfv[n2] = *reinterpret_cast<const bf16x8*>(&Bs[(wc + n2 * 16 + rsel) * 32 + g]);
#pragma unroll
        for (int m = 0; m < 4; m++)
#pragma unroll
            for (int n2 = 0; n2 < 4; n2++)
                acc[m][n2] = __builtin_amdgcn_mfma_f32_16x16x32_bf16(af[m], bfv[n2], acc[m][n2], 0, 0, 0);
        __syncthreads();
    }

    int crow = (lane >> 4) * 4, ccol = lane & 15;
#pragma unroll
    for (int m = 0; m < 4; m++) {
#pragma unroll
        for (int r = 0; r < 4; r++) {
            int row = row0 + wr + m * 16 + crow + r;
            if (row < NN) {
#pragma unroll
                for (int n2 = 0; n2 < 4; n2++)
                    C[(size_t)row * DD + col0 + wc + n2 * 16 + ccol] = f2bf(acc[m][n2][r]);
            }
        }
    }
}

// ---------------- attention scores ----------------

__global__ __launch_bounds__(256) void k_scores(const unsigned short* __restrict__ h,
                                                const float* __restrict__ a_s,
                                                const float* __restrict__ a_d,
                                                float* __restrict__ es,
                                                float* __restrict__ ed) {
    int wid = (blockIdx.x * 256 + threadIdx.x) >> 6;
    int lane = threadIdx.x & 63;
    if (wid >= NN * HH) return;
    int n = wid >> 3, hh = wid & 7;
    float v = bf2f(h[(size_t)n * DD + hh * CC + lane]);
    float ps = v * a_s[hh * CC + lane];
    float pd = v * a_d[hh * CC + lane];
#pragma unroll
    for (int off = 32; off > 0; off >>= 1) {
        ps += __shfl_down(ps, off);
        pd += __shfl_down(pd, off);
    }
    if (lane == 0) { es[wid] = ps; ed[wid] = pd; }
}

// ---------------- GAT aggregation + bias + LayerNorm + ReLU ----------------

__global__ __launch_bounds__(256) void k_gat_agg(const unsigned short* __restrict__ h,
                                                 const float* __restrict__ es,
                                                 const float* __restrict__ ed,
                                                 const int* __restrict__ rowptr,
                                                 const int* __restrict__ csr,
                                                 const float* __restrict__ bias,
                                                 const float* __restrict__ gamma,
                                                 const float* __restrict__ beta,
                                                 unsigned short* __restrict__ xout) {
    int n = blockIdx.x;
    int tid = threadIdx.x;
    int r0 = rowptr[n], r1 = rowptr[n + 1];
    int deg = r1 - r0;
    int d0 = tid * 2;
    int head = tid >> 5;   // (2*tid)>>6

    __shared__ float s_edn[8];
    __shared__ int s_src[64];
    __shared__ float s_p[64][8];
    __shared__ float s_m[8], s_sum[8], s_scale[8];
    __shared__ float red[256];

    if (tid < 8) { s_edn[tid] = ed[n * 8 + tid]; s_m[tid] = -1e30f; s_sum[tid] = 0.f; }
    float acc0 = 0.f, acc1 = 0.f;
    __syncthreads();

    for (int cb = 0; cb < deg; cb += 64) {
        int cnt = min(64, deg - cb);
        if (tid < cnt) s_src[tid] = csr[r0 + cb + tid];
        __syncthreads();
        for (int idx = tid; idx < cnt * 8; idx += 256) {
            int j = idx >> 3, hh = idx & 7;
            float e = es[s_src[j] * 8 + hh] + s_edn[hh];
            s_p[j][hh] = (e >= 0.f) ? e : 0.2f * e;
        }
        __syncthreads();
        if (tid < 8) {
            int hh = tid;
            float cm = -1e30f;
            for (int j = 0; j < cnt; j++) cm = fmaxf(cm, s_p[j][hh]);
            float m_old = s_m[hh];
            float m_new = fmaxf(m_old, cm);
            float scale = __expf(m_old - m_new);
            float csum = 0.f;
            for (int j = 0; j < cnt; j++) {
                float p = __expf(s_p[j][hh] - m_new);
                s_p[j][hh] = p;
                csum += p;
            }
            s_sum[hh] = s_sum[hh] * scale + csum;
            s_m[hh] = m_new;
            s_scale[hh] = scale;
        }
        __syncthreads();
        float sc = s_scale[head];
        acc0 *= sc; acc1 *= sc;
        for (int j = 0; j < cnt; j++) {
            int s = s_src[j];
            unsigned int u = *reinterpret_cast<const unsigned int*>(&h[(size_t)s * DD + d0]);
            float p = s_p[j][head];
            acc0 += p * bf2f((unsigned short)(u & 0xffff));
            acc1 += p * bf2f((unsigned short)(u >> 16));
        }
        __syncthreads();
    }

    float dn = s_sum[head] + 1e-16f;
    float o0 = acc0 / dn + bias[d0];
    float o1 = acc1 / dn + bias[d0 + 1];

    red[tid] = o0 + o1;
    __syncthreads();
    for (int off = 128; off > 0; off >>= 1) {
        if (tid < off) red[tid] += red[tid + off];
        __syncthreads();
    }
    float mu = red[0] * (1.f / 512.f);
    __syncthreads();
    float e0 = o0 - mu, e1 = o1 - mu;
    red[tid] = e0 * e0 + e1 * e1;
    __syncthreads();
    for (int off = 128; off > 0; off >>= 1) {
        if (tid < off) red[tid] += red[tid + off];
        __syncthreads();
    }
    float rs = rsqrtf(red[0] * (1.f / 512.f) + 1e-5f);
    float y0 = fmaxf(e0 * rs * gamma[d0] + beta[d0], 0.f);
    float y1 = fmaxf(e1 * rs * gamma[d0 + 1] + beta[d0 + 1], 0.f);
    unsigned int pack = (unsigned int)f2bf(y0) | ((unsigned int)f2bf(y1) << 16);
    *reinterpret_cast<unsigned int*>(&xout[(size_t)n * DD + d0]) = pack;
}

// ---------------- pooling + FC ----------------

__global__ void k_gbounds(const int* __restrict__ batch, int* __restrict__ gstart) {
    int g = blockIdx.x * blockDim.x + threadIdx.x;
    if (g > GG) return;
    int lo = 0, hi = NN;
    while (lo < hi) {
        int mid = (lo + hi) >> 1;
        if (batch[mid] < g) lo = mid + 1; else hi = mid;
    }
    gstart[g] = lo;
}

__global__ __launch_bounds__(256) void k_pool(const unsigned short* __restrict__ x,
                                              const int* __restrict__ gstart,
                                              float* __restrict__ pooled) {
    int g = blockIdx.x, tid = threadIdx.x;
    int s = gstart[g], e = gstart[g + 1];
    float a0 = 0.f, a1 = 0.f;
    for (int n = s; n < e; n++) {
        unsigned int u = *reinterpret_cast<const unsigned int*>(&x[(size_t)n * DD + tid * 2]);
        a0 += bf2f((unsigned short)(u & 0xffff));
        a1 += bf2f((unsigned short)(u >> 16));
    }
    float inv = 1.f / fmaxf((float)(e - s), 1.f);
    pooled[g * DD + tid * 2] = a0 * inv;
    pooled[g * DD + tid * 2 + 1] = a1 * inv;
}

__global__ __launch_bounds__(128) void k_fc(const float* __restrict__ pooled,
                                            const float* __restrict__ Wf,
                                            const float* __restrict__ bf,
                                            float* __restrict__ out) {
    int g = blockIdx.x, o = threadIdx.x;
    __shared__ float row[DD];
    for (int i = o; i < DD; i += 128) row[i] = pooled[g * DD + i];
    __syncthreads();
    float acc = bf[o];
    for (int d = 0; d < DD; d++) acc += row[d] * Wf[d * OUTD + o];
    out[g * OUTD + o] = acc;
}

// ---------------- launch ----------------

extern "C" void kernel_launch(void* const* d_in, const int* in_sizes, int n_in,
                              void* d_out, int out_size, void* d_ws, size_t ws_size,
                              hipStream_t stream) {
    const float* x     = (const float*)d_in[0];
    const int*   ei    = (const int*)d_in[1];
    const int*   batch = (const int*)d_in[2];
    const float* W[3]  = {(const float*)d_in[3], (const float*)d_in[9],  (const float*)d_in[15]};
    const float* As_[3] = {(const float*)d_in[4], (const float*)d_in[10], (const float*)d_in[16]};
    const float* Ad_[3] = {(const float*)d_in[5], (const float*)d_in[11], (const float*)d_in[17]};
    const float* Bi[3] = {(const float*)d_in[6], (const float*)d_in[12], (const float*)d_in[18]};
    const float* Ga[3] = {(const float*)d_in[7], (const float*)d_in[13], (const float*)d_in[19]};
    const float* Be[3] = {(const float*)d_in[8], (const float*)d_in[14], (const float*)d_in[20]};
    const float* fcW = (const float*)d_in[21];
    const float* fcb = (const float*)d_in[22];
    float* out = (float*)d_out;

    char* p = (char*)d_ws;
    auto carve = [&](size_t bytes) {
        char* r = p;
        p += (bytes + 255) & ~((size_t)255);
        return r;
    };
    unsigned short* xb0  = (unsigned short*)carve((size_t)MPAD * DD * 2);
    unsigned short* xb1  = (unsigned short*)carve((size_t)MPAD * DD * 2);
    unsigned short* hbuf = (unsigned short*)carve((size_t)MPAD * DD * 2);
    unsigned short* Wt   = (unsigned short*)carve((size_t)DD * DD * 2);
    float* es     = (float*)carve((size_t)NN * HH * 4);
    float* ed     = (float*)carve((size_t)NN * HH * 4);
    int*   deg    = (int*)carve((size_t)NN * 4);
    int*   rowptr = (int*)carve((size_t)(NN + 1) * 4);
    int*   wp     = (int*)carve((size_t)NN * 4);
    int*   csr    = (int*)carve((size_t)ETOT * 4);
    int*   gstart = (int*)carve((size_t)(GG + 1) * 4);
    float* pooled = (float*)carve((size_t)GG * DD * 4);

    // CSR build
    hipMemsetAsync(deg, 0, (size_t)NN * 4, stream);
    k_degree<<<(ETOT + 255) / 256, 256, 0, stream>>>(ei, deg);
    k_scan<<<1, 1024, 0, stream>>>(deg, rowptr);
    hipMemcpyAsync(wp, rowptr, (size_t)NN * 4, hipMemcpyDeviceToDevice, stream);
    k_scatter<<<(ETOT + 255) / 256, 256, 0, stream>>>(ei, wp, csr);
    k_gbounds<<<1, 256, 0, stream>>>(batch, gstart);

    // zero pad rows of xb1 (xb0's pad is zeroed by k_cast_x)
    hipMemsetAsync(xb1 + (size_t)NN * DD, 0, (size_t)(MPAD - NN) * DD * 2, stream);
    k_cast_x<<<(MPAD * DD / 4 + 255) / 256, 256, 0, stream>>>(x, xb0);

    unsigned short* xin = xb0;
    unsigned short* xnext = xb1;
    for (int l = 0; l < 3; l++) {
        k_wt<<<dim3(16, 16), dim3(32, 8), 0, stream>>>(W[l], Wt);
        k_gemm<<<dim3(MPAD / 128, 4), 256, 0, stream>>>(xin, Wt, hbuf);
        k_scores<<<(NN * HH) / 4, 256, 0, stream>>>(hbuf, As_[l], Ad_[l], es, ed);
        k_gat_agg<<<NN, 256, 0, stream>>>(hbuf, es, ed, rowptr, csr,
                                          Bi[l], Ga[l], Be[l], xnext);
        unsigned short* t = xin; xin = xnext; xnext = t;
    }

    // after 3 swaps, final output is in xin
    k_pool<<<GG, 256, 0, stream>>>(xin, gstart, pooled);
    k_fc<<<GG, 128, 0, stream>>>(pooled, fcW, fcb, out);
}

// Round 9
// 510.507 us; speedup vs baseline: 1.8732x; 1.1057x over previous
//
#include <hip/hip_runtime.h>
#include <hip/hip_bf16.h>

#define NN 20000
#define MPAD 20096          // 157 * 128
#define EE 160000
#define ETOT 180000         // edges + self loops
#define HH 8
#define DD 512
#define CC 64
#define GG 128
#define OUTD 128

typedef __bf16 bf16x8 __attribute__((ext_vector_type(8)));
typedef unsigned short u16x8 __attribute__((ext_vector_type(8)));
typedef float f32x4 __attribute__((ext_vector_type(4)));

__device__ __forceinline__ float bf2f(unsigned short u) {
    unsigned int x = ((unsigned int)u) << 16;
    return __builtin_bit_cast(float, x);
}
__device__ __forceinline__ unsigned short f2bf(float f) {
    unsigned int x = __builtin_bit_cast(unsigned int, f);
    unsigned int r = (x + 0x7fff + ((x >> 16) & 1)) >> 16;
    return (unsigned short)r;
}

// ---------------- CSR build ----------------

__global__ void k_degree(const int* __restrict__ ei, int* __restrict__ deg) {
    int e = blockIdx.x * blockDim.x + threadIdx.x;
    if (e >= ETOT) return;
    int dst = (e < EE) ? ei[EE + e] : (e - EE);
    atomicAdd(&deg[dst], 1);
}

__global__ __launch_bounds__(1024) void k_scan(const int* __restrict__ deg,
                                               int* __restrict__ rowptr) {
    __shared__ int part[1024];
    const int n = NN;
    const int per = (n + 1023) / 1024;
    int base = threadIdx.x * per;
    int s = 0;
    for (int i = 0; i < per; i++) {
        int idx = base + i;
        if (idx < n) s += deg[idx];
    }
    part[threadIdx.x] = s;
    __syncthreads();
    for (int off = 1; off < 1024; off <<= 1) {
        int v = 0;
        if ((int)threadIdx.x >= off) v = part[threadIdx.x - off];
        __syncthreads();
        part[threadIdx.x] += v;
        __syncthreads();
    }
    int run = (threadIdx.x == 0) ? 0 : part[threadIdx.x - 1];
    for (int i = 0; i < per; i++) {
        int idx = base + i;
        if (idx < n) { rowptr[idx] = run; run += deg[idx]; }
    }
    if (threadIdx.x == 1023) rowptr[n] = part[1023];
}

__global__ void k_scatter(const int* __restrict__ ei, int* __restrict__ wp,
                          int* __restrict__ csr) {
    int e = blockIdx.x * blockDim.x + threadIdx.x;
    if (e >= ETOT) return;
    int src, dst;
    if (e < EE) { src = ei[e]; dst = ei[EE + e]; }
    else        { src = e - EE; dst = e - EE; }
    int pos = atomicAdd(&wp[dst], 1);
    csr[pos] = src;
}

// ---------------- f32 -> bf16 cast (with zero pad rows) ----------------

__global__ __launch_bounds__(256) void k_cast_x(const float* __restrict__ x,
                                                unsigned short* __restrict__ xb) {
    long long i = (long long)(blockIdx.x * 256 + threadIdx.x) * 4;
    if (i >= (long long)MPAD * DD) return;
    ushort4 o;
    if (i < (long long)NN * DD) {
        float4 v = *reinterpret_cast<const float4*>(&x[i]);
        o.x = f2bf(v.x); o.y = f2bf(v.y); o.z = f2bf(v.z); o.w = f2bf(v.w);
    } else {
        o = make_ushort4(0, 0, 0, 0);
    }
    *reinterpret_cast<ushort4*>(&xb[i]) = o;
}

// ---------------- W transpose + cast: Wt[n][k] = bf16(W[k][n]) ----------------

__global__ __launch_bounds__(256) void k_wt(const float* __restrict__ W,
                                            unsigned short* __restrict__ Wt) {
    __shared__ float t[32][33];
    int tx = threadIdx.x, ty = threadIdx.y;
    int bk = blockIdx.x * 32, bn = blockIdx.y * 32;
#pragma unroll
    for (int j = 0; j < 4; j++)
        t[ty + j * 8][tx] = W[(bk + ty + j * 8) * DD + bn + tx];
    __syncthreads();
#pragma unroll
    for (int j = 0; j < 4; j++)
        Wt[(bn + ty + j * 8) * DD + bk + tx] = f2bf(t[tx][ty + j * 8]);
}

// ---------------- bf16 MFMA GEMM (m97 structure, 128x128 tile, BK=32) ----------------

__global__ __launch_bounds__(256) void k_gemm(const unsigned short* __restrict__ A,
                                              const unsigned short* __restrict__ Bt,
                                              unsigned short* __restrict__ C) {
    __shared__ alignas(16) unsigned short As[128 * 32];
    __shared__ alignas(16) unsigned short Bs[128 * 32];
    int tid = threadIdx.x;
    int lane = tid & 63, wv = tid >> 6;
    int row0 = blockIdx.x * 128, col0 = blockIdx.y * 128;
    int wr = (wv >> 1) * 64, wc = (wv & 1) * 64;
    f32x4 acc[4][4] = {};
    int srow = lane >> 2;
    int sel = (lane & 3) * 8;

    for (int k0 = 0; k0 < DD; k0 += 32) {
#pragma unroll
        for (int i = 0; i < 2; i++) {
            int tr = wv * 32 + i * 16 + srow;
            __builtin_amdgcn_global_load_lds(
                (const __attribute__((address_space(1))) unsigned int*)&A[(size_t)(row0 + tr) * DD + k0 + sel],
                (__attribute__((address_space(3))) unsigned int*)&As[(wv * 32 + i * 16) * 32],
                16, 0, 0);
            __builtin_amdgcn_global_load_lds(
                (const __attribute__((address_space(1))) unsigned int*)&Bt[(size_t)(col0 + tr) * DD + k0 + sel],
                (__attribute__((address_space(3))) unsigned int*)&Bs[(wv * 32 + i * 16) * 32],
                16, 0, 0);
        }
        __syncthreads();
        bf16x8 af[4], bfv[4];
        int rsel = lane & 15, g = (lane >> 4) * 8;
#pragma unroll
        for (int m = 0; m < 4; m++)
            af[m] = *reinterpret_cast<const bf16x8*>(&As[(wr + m * 16 + rsel) * 32 + g]);
#pragma unroll
        for (int n2 = 0; n2 < 4; n2++)
            bfv[n2] = *reinterpret_cast<const bf16x8*>(&Bs[(wc + n2 * 16 + rsel) * 32 + g]);
#pragma unroll
        for (int m = 0; m < 4; m++)
#pragma unroll
            for (int n2 = 0; n2 < 4; n2++)
                acc[m][n2] = __builtin_amdgcn_mfma_f32_16x16x32_bf16(af[m], bfv[n2], acc[m][n2], 0, 0, 0);
        __syncthreads();
    }

    int crow = (lane >> 4) * 4, ccol = lane & 15;
#pragma unroll
    for (int m = 0; m < 4; m++) {
#pragma unroll
        for (int r = 0; r < 4; r++) {
            int row = row0 + wr + m * 16 + crow + r;
            if (row < NN) {
#pragma unroll
                for (int n2 = 0; n2 < 4; n2++)
                    C[(size_t)row * DD + col0 + wc + n2 * 16 + ccol] = f2bf(acc[m][n2][r]);
            }
        }
    }
}

// ---------------- attention scores ----------------

__global__ __launch_bounds__(256) void k_scores(const unsigned short* __restrict__ h,
                                                const float* __restrict__ a_s,
                                                const float* __restrict__ a_d,
                                                float* __restrict__ es,
                                                float* __restrict__ ed) {
    int wid = (blockIdx.x * 256 + threadIdx.x) >> 6;
    int lane = threadIdx.x & 63;
    if (wid >= NN * HH) return;
    int n = wid >> 3, hh = wid & 7;
    float v = bf2f(h[(size_t)n * DD + hh * CC + lane]);
    float ps = v * a_s[hh * CC + lane];
    float pd = v * a_d[hh * CC + lane];
#pragma unroll
    for (int off = 32; off > 0; off >>= 1) {
        ps += __shfl_down(ps, off);
        pd += __shfl_down(pd, off);
    }
    if (lane == 0) { es[wid] = ps; ed[wid] = pd; }
}

// ---------------- edge softmax: unnormalized p per CSR slot + inverse denom ----------------
// one thread per (node, head)

__global__ __launch_bounds__(256) void k_alpha(const float* __restrict__ es,
                                               const float* __restrict__ ed,
                                               const int* __restrict__ rowptr,
                                               const int* __restrict__ csr,
                                               float* __restrict__ alpha,
                                               float* __restrict__ invden) {
    int id = blockIdx.x * 256 + threadIdx.x;
    if (id >= NN * HH) return;
    int n = id >> 3, hh = id & 7;
    int r0 = rowptr[n], r1 = rowptr[n + 1];
    float edn = ed[id];
    float m = -1e30f;
    for (int j = r0; j < r1; j++) {
        float e = es[csr[j] * 8 + hh] + edn;
        e = (e >= 0.f) ? e : 0.2f * e;
        m = fmaxf(m, e);
    }
    float sum = 0.f;
    for (int j = r0; j < r1; j++) {
        float e = es[csr[j] * 8 + hh] + edn;
        e = (e >= 0.f) ? e : 0.2f * e;
        float pv = __expf(e - m);
        alpha[(size_t)j * 8 + hh] = pv;
        sum += pv;
    }
    invden[id] = 1.f / (sum + 1e-16f);
}

// ---------------- gather-aggregate + bias + LayerNorm + ReLU ----------------
// one wave per node, 4 waves/block, no __syncthreads; lane owns 8 contiguous dims

__global__ __launch_bounds__(256) void k_aggln(const unsigned short* __restrict__ h,
                                               const float* __restrict__ alpha,
                                               const float* __restrict__ invden,
                                               const int* __restrict__ rowptr,
                                               const int* __restrict__ csr,
                                               const float* __restrict__ bias,
                                               const float* __restrict__ gamma,
                                               const float* __restrict__ beta,
                                               unsigned short* __restrict__ xout) {
    int wv = threadIdx.x >> 6, lane = threadIdx.x & 63;
    int n = blockIdx.x * 4 + wv;
    int r0 = rowptr[n], r1 = rowptr[n + 1];
    int head = lane >> 3;
    int d0 = lane * 8;

    float acc[8] = {};
    for (int j = r0; j < r1; j++) {
        int s = csr[j];
        float p = alpha[(size_t)j * 8 + head];
        u16x8 hv = *reinterpret_cast<const u16x8*>(&h[(size_t)s * DD + d0]);
#pragma unroll
        for (int k = 0; k < 8; k++) acc[k] += p * bf2f(hv[k]);
    }

    float inv = invden[n * 8 + head];
    float s1 = 0.f, s2 = 0.f;
#pragma unroll
    for (int k = 0; k < 8; k++) {
        acc[k] = acc[k] * inv + bias[d0 + k];
        s1 += acc[k];
        s2 += acc[k] * acc[k];
    }
#pragma unroll
    for (int off = 1; off < 64; off <<= 1) {
        s1 += __shfl_xor(s1, off);
        s2 += __shfl_xor(s2, off);
    }
    float mu = s1 * (1.f / 512.f);
    float var = s2 * (1.f / 512.f) - mu * mu;
    float rs = rsqrtf(var + 1e-5f);

    u16x8 o;
#pragma unroll
    for (int k = 0; k < 8; k++) {
        float y = (acc[k] - mu) * rs * gamma[d0 + k] + beta[d0 + k];
        o[k] = f2bf(fmaxf(y, 0.f));
    }
    *reinterpret_cast<u16x8*>(&xout[(size_t)n * DD + d0]) = o;
}

// ---------------- pooling + FC ----------------

__global__ void k_gbounds(const int* __restrict__ batch, int* __restrict__ gstart) {
    int g = blockIdx.x * blockDim.x + threadIdx.x;
    if (g > GG) return;
    int lo = 0, hi = NN;
    while (lo < hi) {
        int mid = (lo + hi) >> 1;
        if (batch[mid] < g) lo = mid + 1; else hi = mid;
    }
    gstart[g] = lo;
}

__global__ __launch_bounds__(256) void k_pool(const unsigned short* __restrict__ x,
                                              const int* __restrict__ gstart,
                                              float* __restrict__ pooled) {
    int g = blockIdx.x, tid = threadIdx.x;
    int s = gstart[g], e = gstart[g + 1];
    float a0 = 0.f, a1 = 0.f;
    for (int n = s; n < e; n++) {
        unsigned int u = *reinterpret_cast<const unsigned int*>(&x[(size_t)n * DD + tid * 2]);
        a0 += bf2f((unsigned short)(u & 0xffff));
        a1 += bf2f((unsigned short)(u >> 16));
    }
    float inv = 1.f / fmaxf((float)(e - s), 1.f);
    pooled[g * DD + tid * 2] = a0 * inv;
    pooled[g * DD + tid * 2 + 1] = a1 * inv;
}

__global__ __launch_bounds__(128) void k_fc(const float* __restrict__ pooled,
                                            const float* __restrict__ Wf,
                                            const float* __restrict__ bf,
                                            float* __restrict__ out) {
    int g = blockIdx.x, o = threadIdx.x;
    __shared__ float row[DD];
    for (int i = o; i < DD; i += 128) row[i] = pooled[g * DD + i];
    __syncthreads();
    float acc = bf[o];
    for (int d = 0; d < DD; d++) acc += row[d] * Wf[d * OUTD + o];
    out[g * OUTD + o] = acc;
}

// ---------------- launch ----------------

extern "C" void kernel_launch(void* const* d_in, const int* in_sizes, int n_in,
                              void* d_out, int out_size, void* d_ws, size_t ws_size,
                              hipStream_t stream) {
    const float* x     = (const float*)d_in[0];
    const int*   ei    = (const int*)d_in[1];
    const int*   batch = (const int*)d_in[2];
    const float* W[3]  = {(const float*)d_in[3], (const float*)d_in[9],  (const float*)d_in[15]};
    const float* As_[3] = {(const float*)d_in[4], (const float*)d_in[10], (const float*)d_in[16]};
    const float* Ad_[3] = {(const float*)d_in[5], (const float*)d_in[11], (const float*)d_in[17]};
    const float* Bi[3] = {(const float*)d_in[6], (const float*)d_in[12], (const float*)d_in[18]};
    const float* Ga[3] = {(const float*)d_in[7], (const float*)d_in[13], (const float*)d_in[19]};
    const float* Be[3] = {(const float*)d_in[8], (const float*)d_in[14], (const float*)d_in[20]};
    const float* fcW = (const float*)d_in[21];
    const float* fcb = (const float*)d_in[22];
    float* out = (float*)d_out;

    char* p = (char*)d_ws;
    auto carve = [&](size_t bytes) {
        char* r = p;
        p += (bytes + 255) & ~((size_t)255);
        return r;
    };
    unsigned short* xb0  = (unsigned short*)carve((size_t)MPAD * DD * 2);
    unsigned short* xb1  = (unsigned short*)carve((size_t)MPAD * DD * 2);
    unsigned short* hbuf = (unsigned short*)carve((size_t)MPAD * DD * 2);
    unsigned short* Wt   = (unsigned short*)carve((size_t)DD * DD * 2);
    float* es     = (float*)carve((size_t)NN * HH * 4);
    float* ed     = (float*)carve((size_t)NN * HH * 4);
    float* alpha  = (float*)carve((size_t)ETOT * HH * 4);
    float* invden = (float*)carve((size_t)NN * HH * 4);
    int*   deg    = (int*)carve((size_t)NN * 4);
    int*   rowptr = (int*)carve((size_t)(NN + 1) * 4);
    int*   wp     = (int*)carve((size_t)NN * 4);
    int*   csr    = (int*)carve((size_t)ETOT * 4);
    int*   gstart = (int*)carve((size_t)(GG + 1) * 4);
    float* pooled = (float*)carve((size_t)GG * DD * 4);

    // CSR build
    hipMemsetAsync(deg, 0, (size_t)NN * 4, stream);
    k_degree<<<(ETOT + 255) / 256, 256, 0, stream>>>(ei, deg);
    k_scan<<<1, 1024, 0, stream>>>(deg, rowptr);
    hipMemcpyAsync(wp, rowptr, (size_t)NN * 4, hipMemcpyDeviceToDevice, stream);
    k_scatter<<<(ETOT + 255) / 256, 256, 0, stream>>>(ei, wp, csr);
    k_gbounds<<<1, 256, 0, stream>>>(batch, gstart);

    // zero pad rows of xb1 (xb0's pad is zeroed by k_cast_x)
    hipMemsetAsync(xb1 + (size_t)NN * DD, 0, (size_t)(MPAD - NN) * DD * 2, stream);
    k_cast_x<<<(MPAD * DD / 4 + 255) / 256, 256, 0, stream>>>(x, xb0);

    unsigned short* xin = xb0;
    unsigned short* xnext = xb1;
    for (int l = 0; l < 3; l++) {
        k_wt<<<dim3(16, 16), dim3(32, 8), 0, stream>>>(W[l], Wt);
        k_gemm<<<dim3(MPAD / 128, 4), 256, 0, stream>>>(xin, Wt, hbuf);
        k_scores<<<(NN * HH) / 4, 256, 0, stream>>>(hbuf, As_[l], Ad_[l], es, ed);
        k_alpha<<<(NN * HH + 255) / 256, 256, 0, stream>>>(es, ed, rowptr, csr, alpha, invden);
        k_aggln<<<NN / 4, 256, 0, stream>>>(hbuf, alpha, invden, rowptr, csr,
                                            Bi[l], Ga[l], Be[l], xnext);
        unsigned short* t = xin; xin = xnext; xnext = t;
    }

    // after 3 swaps, final output is in xin
    k_pool<<<GG, 256, 0, stream>>>(xin, gstart, pooled);
    k_fc<<<GG, 128, 0, stream>>>(pooled, fcW, fcb, out);
}